// Round 1
// baseline (217.720 us; speedup 1.0000x reference)
//
#include <hip/hip_runtime.h>

// out = x * diag (broadcast over last axis). x: 32768 x 4096 f32, diag: 4096 f32.
// Memory-bound: float4 loads (16B/lane), grid-stride loop over 2048 blocks.

#define CHANNELS 4096
#define CH4 (CHANNELS / 4)   // 1024 float4 per row

__global__ void DiagonalLinear_80960133529733_kernel(const float4* __restrict__ x,
                                                     const float4* __restrict__ diag,
                                                     float4* __restrict__ out,
                                                     long long n4) {
    long long i = (long long)blockIdx.x * blockDim.x + threadIdx.x;
    const long long stride = (long long)gridDim.x * blockDim.x;
    for (; i < n4; i += stride) {
        float4 xv = x[i];
        float4 dv = diag[i & (CH4 - 1)];   // channel index = (i*4) % 4096 → float4 idx i % 1024
        float4 o;
        o.x = xv.x * dv.x;
        o.y = xv.y * dv.y;
        o.z = xv.z * dv.z;
        o.w = xv.w * dv.w;
        out[i] = o;
    }
}

extern "C" void kernel_launch(void* const* d_in, const int* in_sizes, int n_in,
                              void* d_out, int out_size, void* d_ws, size_t ws_size,
                              hipStream_t stream) {
    const float* x    = (const float*)d_in[0];
    const float* diag = (const float*)d_in[1];
    float* out        = (float*)d_out;

    const long long n  = (long long)in_sizes[0];   // 32768*4096 elements
    const long long n4 = n / 4;                    // exactly divisible (4096 % 4 == 0)

    const int block = 256;
    // Memory-bound: cap grid at ~8 blocks/CU * 256 CU = 2048, grid-stride the rest.
    long long want = (n4 + block - 1) / block;
    int grid = (int)(want < 2048 ? want : 2048);

    DiagonalLinear_80960133529733_kernel<<<grid, block, 0, stream>>>(
        (const float4*)x, (const float4*)diag, (float4*)out, n4);
}